// Round 6
// baseline (249.160 us; speedup 1.0000x reference)
//
#include <hip/hip_runtime.h>

constexpr int N_DOCS = 4096;
constexpr int N_QS   = 8192;
constexpr int BLOCK  = 256;
constexpr int VEC_PER_THREAD = N_QS / 4 / BLOCK;  // 8 16B-loads per thread per array

// Native Clang vector types — __builtin_nontemporal_load requires these.
typedef float fx4 __attribute__((ext_vector_type(4)));
typedef int   ix4 __attribute__((ext_vector_type(4)));

// One block per row.
// R5: nt loads (no L2/L3 allocation) won 25% — dirty-L3 writeback theory
// partially confirmed. But nt loads see full L3/HBM latency, so the R2
// MLP problem is back: compiler sinks staged loads (VGPR=36, ~3 in flight).
// Fix: pin the schedule — issue ALL 16 independent loads, sched_barrier(0),
// then consume. 16 KB in flight per wave covers ~900cyc latency.
__global__ __launch_bounds__(BLOCK) void row_reduce_kernel(
    const fx4* __restrict__ cos4,
    const ix4* __restrict__ mask4,
    float2* __restrict__ row_out)
{
    const int row = blockIdx.x;
    const int tid = threadIdx.x;
    const long base = (long)row * (N_QS / 4);

    // ---- load phase: 16 independent nt 16B loads ----
    fx4 c[VEC_PER_THREAD];
    ix4 m[VEC_PER_THREAD];
#pragma unroll
    for (int v = 0; v < VEC_PER_THREAD; ++v) {
        const int idx = v * BLOCK + tid;          // coalesced
        c[v] = __builtin_nontemporal_load(&cos4[base + idx]);
        m[v] = __builtin_nontemporal_load(&mask4[base + idx]);
    }
    // Hard scheduling fence: nothing moves across. Loads cannot sink into
    // the consume loop; consume cannot hoist above.
    __builtin_amdgcn_sched_barrier(0);

    // ---- compute phase: 6 VALU ops/elem ----
    // s_t = sum m*(1-c) = cnt - sum(m?c:0); cnt accumulated as int
    // (mask_gt is randint(0,2) -> values are exactly 0/1).
    float s_mc = 0.f, s_nt = 0.f;
    int   icnt = 0;
#pragma unroll
    for (int v = 0; v < VEC_PER_THREAD; ++v) {
        s_mc += (m[v].x != 0) ? c[v].x : 0.f;
        s_mc += (m[v].y != 0) ? c[v].y : 0.f;
        s_mc += (m[v].z != 0) ? c[v].z : 0.f;
        s_mc += (m[v].w != 0) ? c[v].w : 0.f;

        s_nt += (m[v].x != 0) ? 0.f : fmaxf(c[v].x, 0.f);
        s_nt += (m[v].y != 0) ? 0.f : fmaxf(c[v].y, 0.f);
        s_nt += (m[v].z != 0) ? 0.f : fmaxf(c[v].z, 0.f);
        s_nt += (m[v].w != 0) ? 0.f : fmaxf(c[v].w, 0.f);

        icnt += m[v].x + m[v].y + m[v].z + m[v].w;
    }

    // Wave-64 shuffle reduction
    float cf = (float)icnt;
#pragma unroll
    for (int off = 32; off > 0; off >>= 1) {
        s_mc += __shfl_down(s_mc, off);
        s_nt += __shfl_down(s_nt, off);
        cf   += __shfl_down(cf,   off);
    }

    // Cross-wave reduction (4 waves)
    __shared__ float red_mc[4], red_nt[4], red_c[4];
    const int wave = tid >> 6;
    const int lane = tid & 63;
    if (lane == 0) {
        red_mc[wave] = s_mc;
        red_nt[wave] = s_nt;
        red_c[wave]  = cf;
    }
    __syncthreads();

    if (tid == 0) {
        float mc = 0.f, nt = 0.f, ct = 0.f;
#pragma unroll
        for (int w = 0; w < 4; ++w) { mc += red_mc[w]; nt += red_nt[w]; ct += red_c[w]; }
        float t      = ct - mc;               // sum m*(1-c)
        float cnt_nt = (float)N_QS - ct;
        row_out[row] = make_float2(t / ct, nt / cnt_nt);
    }
}

// Single-block final reduction over 4096 row results.
__global__ __launch_bounds__(1024) void final_reduce_kernel(
    const float2* __restrict__ row_out,
    float* __restrict__ out)
{
    const int tid = threadIdx.x;
    float a = 0.f, b = 0.f;
#pragma unroll
    for (int i = tid; i < N_DOCS; i += 1024) {
        float2 r = row_out[i];
        a += r.x;
        b += r.y;
    }
#pragma unroll
    for (int off = 32; off > 0; off >>= 1) {
        a += __shfl_down(a, off);
        b += __shfl_down(b, off);
    }
    __shared__ float sa[16], sb[16];
    const int wave = tid >> 6;
    const int lane = tid & 63;
    if (lane == 0) { sa[wave] = a; sb[wave] = b; }
    __syncthreads();
    if (tid == 0) {
        float ta = 0.f, tb = 0.f;
#pragma unroll
        for (int w = 0; w < 16; ++w) { ta += sa[w]; tb += sb[w]; }
        float loss_tgt    = ta / (float)N_DOCS;
        float loss_nontgt = tb / (float)N_DOCS;
        out[0] = (loss_tgt + loss_nontgt) * 0.5f;  // loss
        out[1] = loss_tgt;                          // loss_tgt
        out[2] = loss_nontgt;                       // loss_nontgt
    }
}

extern "C" void kernel_launch(void* const* d_in, const int* in_sizes, int n_in,
                              void* d_out, int out_size, void* d_ws, size_t ws_size,
                              hipStream_t stream) {
    const fx4* cos4  = (const fx4*)d_in[0];   // cos_pred fp32 [4096,8192]
    const ix4* mask4 = (const ix4*)d_in[1];   // mask_gt  int32 [4096,8192]
    float2* row_out = (float2*)d_ws;          // 4096 * 8 B = 32 KiB scratch
    float*  out     = (float*)d_out;          // 3 fp32 scalars

    row_reduce_kernel<<<N_DOCS, BLOCK, 0, stream>>>(cos4, mask4, row_out);
    final_reduce_kernel<<<1, 1024, 0, stream>>>(row_out, out);
}